// Round 13
// baseline (327.375 us; speedup 1.0000x reference)
//
#include <hip/hip_runtime.h>

// ---------------------------------------------------------------------------
// StandardGCN: 3-layer GCN, N=50000 nodes, E=800000 edges, D=H=128, OUT=2.
//   CSR build via deterministic 2-level bucket sort (NO global atomics):
//     k_bcount -> k_bscan -> k_bfill -> k_csort (see round-10 notes).
//   gemm128: f32 GEMM, 128-row tiles, 8x8 register blocking, ALL LDS reads
//     vectorized b128 (round-10 profile: 8 scalar ds_read_b32 per k made the
//     kernel LDS-issue-bound at 43us; this cuts LDS issue cycles ~3x).
//   agg128: pull aggregation over bf16 H (f32 accum). Layer 3 transforms
//   first (128->2) then aggregates.
//   Requires n <= 16M (24-bit src packing) and 256-node buckets.
// ---------------------------------------------------------------------------

typedef unsigned short ushort_t;
typedef unsigned int uint_t;

#define NBLK 128          // blocks for bcount/bfill
#define BCAP 6144         // per-bucket LDS capacity (mean 4096, +32 sigma)

static __device__ __forceinline__ ushort_t f2bf(float f) {
    uint_t u = __float_as_uint(f);
    u += 0x7FFFu + ((u >> 16) & 1u);   // round-to-nearest-even
    return (ushort_t)(u >> 16);
}
static __device__ __forceinline__ float bf_lo(uint_t u) {
    return __uint_as_float(u << 16);
}
static __device__ __forceinline__ float bf_hi(uint_t u) {
    return __uint_as_float(u & 0xFFFF0000u);
}

// --- pass 1: per-block bucket histogram (no global atomics) ---------------
__global__ __launch_bounds__(256) void k_bcount(const int* __restrict__ dst, int E,
                                                int* __restrict__ cntmat, int NB) {
    __shared__ int hist[256];
    int t = threadIdx.x;
    hist[t] = 0;
    __syncthreads();
    int chunk = (E + NBLK - 1) / NBLK;
    int e0 = blockIdx.x * chunk;
    int e1 = min(e0 + chunk, E);
    for (int e = e0 + t; e < e1; e += 256) {
        atomicAdd(&hist[dst[e] >> 8], 1);
    }
    __syncthreads();
    if (t < NB) cntmat[blockIdx.x * NB + t] = hist[t];
}

// --- pass 2: column scan of cntmat + bucket base scan ---------------------
__global__ __launch_bounds__(256) void k_bscan(int* __restrict__ cntmat,
                                               int* __restrict__ bktbase,
                                               int* __restrict__ rowptr,
                                               int NB, int n, int E) {
    __shared__ int s[256];
    int t = threadIdx.x;
    int acc = 0;
    if (t < NB) {
        for (int r = 0; r < NBLK; r++) {
            int idx = r * NB + t;
            int c = cntmat[idx];
            cntmat[idx] = acc;    // within-bucket cross-block exclusive offset
            acc += c;
        }
    }
    s[t] = acc;                   // column total (0 for t >= NB)
    __syncthreads();
    for (int off = 1; off < 256; off <<= 1) {
        int u = (t >= off) ? s[t - off] : 0;
        __syncthreads();
        s[t] += u;
        __syncthreads();
    }
    if (t <= NB) bktbase[t] = s[t] - ((t < NB) ? acc : 0);  // exclusive; [NB]=E
    if (t == 0) rowptr[n] = E;
}

// --- pass 3: binned scatter into bucketed[] (LDS claims, run-coalesced) ---
__global__ __launch_bounds__(256) void k_bfill(const int* __restrict__ src,
                                               const int* __restrict__ dst, int E,
                                               const int* __restrict__ cntmat,
                                               const int* __restrict__ bktbase,
                                               uint_t* __restrict__ bucketed, int NB) {
    __shared__ int runb[256];
    __shared__ int bb[257];
    __shared__ int cur[256];
    int t = threadIdx.x;
    if (t < NB) {
        runb[t] = cntmat[blockIdx.x * NB + t];
        cur[t] = 0;
    }
    if (t < NB + 1) bb[t] = bktbase[t];
    __syncthreads();
    int chunk = (E + NBLK - 1) / NBLK;
    int e0 = blockIdx.x * chunk;
    int e1 = min(e0 + chunk, E);
    for (int e = e0 + t; e < e1; e += 256) {
        int d = dst[e];
        int b = d >> 8;
        int slot = atomicAdd(&cur[b], 1);
        bucketed[bb[b] + runb[b] + slot] = ((uint_t)src[e] << 8) | (uint_t)(d & 255);
    }
}

// --- pass 4: per-bucket counting sort -> csr_src, rowptr, dis -------------
__global__ __launch_bounds__(256) void k_csort(const uint_t* __restrict__ bucketed,
                                               const int* __restrict__ bktbase,
                                               int* __restrict__ rowptr,
                                               float* __restrict__ dis,
                                               int* __restrict__ csr_src, int n) {
    __shared__ int ncnt[256];
    __shared__ int s[256];
    __shared__ int cur[256];
    __shared__ int sorted[BCAP];
    int t = threadIdx.x;
    int b = blockIdx.x;
    int base = bktbase[b];
    int cnt_b = bktbase[b + 1] - base;
    int d0 = b << 8;

    ncnt[t] = 0;
    __syncthreads();
    for (int i = t; i < cnt_b; i += 256) {
        atomicAdd(&ncnt[bucketed[base + i] & 255u], 1);
    }
    __syncthreads();
    int own = ncnt[t];
    s[t] = own;
    __syncthreads();
    for (int off = 1; off < 256; off <<= 1) {
        int u = (t >= off) ? s[t - off] : 0;
        __syncthreads();
        s[t] += u;
        __syncthreads();
    }
    int ex = s[t] - own;          // exclusive within-bucket offset
    cur[t] = ex;
    int d = d0 + t;
    if (d < n) {
        rowptr[d] = base + ex;
        dis[d] = rsqrtf((float)(own + 1));
    }
    __syncthreads();
    for (int i = t; i < cnt_b; i += 256) {
        uint_t ent = bucketed[base + i];
        int p = atomicAdd(&cur[ent & 255u], 1);
        if (p < BCAP) sorted[p] = (int)(ent >> 8);
    }
    __syncthreads();
    for (int i = t; i < cnt_b; i += 256) {
        csr_src[base + i] = sorted[i];
    }
}

// --- C[n x 128](bf16) = A[n x 128](f32) @ W[128 x 128](f32) ---------------
// 128 rows/block, 256 threads, 8x8 register blocking, all-b128 LDS reads.
// LDS: A-tile 64KB + W chunk 16KB = 80KB -> 2 blocks/CU.
__global__ __launch_bounds__(256) void k_gemm128(const float* __restrict__ A,
                                                 const float* __restrict__ W,
                                                 ushort_t* __restrict__ C, int n) {
    __shared__ float As[128 * 128];
    __shared__ float Wc[32 * 128];
    int t = threadIdx.x;
    int r0 = blockIdx.x * 128;

    // stage A rows r0..r0+127: 4096 float4, 16 per thread
    for (int i = t; i < 128 * 32; i += 256) {
        int gr = r0 + (i >> 5);
        float4 val = (gr < n) ? ((const float4*)A)[(size_t)gr * 32 + (i & 31)]
                              : make_float4(0.f, 0.f, 0.f, 0.f);
        ((float4*)As)[i] = val;
    }

    int c8 = (t & 15) * 8;       // 8 consecutive cols
    int r8 = (t >> 4) * 8;       // 8 consecutive rows
    float acc[8][8] = {};

    for (int kc = 0; kc < 4; kc++) {
        __syncthreads();
        // stage W rows kc*32..kc*32+31: 1024 float4, 4 per thread
        for (int i = t; i < 32 * 32; i += 256) {
            ((float4*)Wc)[i] = ((const float4*)W)[kc * 1024 + i];
        }
        __syncthreads();
#pragma unroll
        for (int k4 = 0; k4 < 32; k4 += 4) {
            float4 a[8];
#pragma unroll
            for (int i = 0; i < 8; i++) {
                a[i] = *(const float4*)&As[(r8 + i) * 128 + kc * 32 + k4];
            }
            float4 w[4][2];
#pragma unroll
            for (int kk = 0; kk < 4; kk++) {
                w[kk][0] = *(const float4*)&Wc[(k4 + kk) * 128 + c8];
                w[kk][1] = *(const float4*)&Wc[(k4 + kk) * 128 + c8 + 4];
            }
#pragma unroll
            for (int i = 0; i < 8; i++) {
                float av[4] = {a[i].x, a[i].y, a[i].z, a[i].w};
#pragma unroll
                for (int kk = 0; kk < 4; kk++) {
                    acc[i][0] += av[kk] * w[kk][0].x;
                    acc[i][1] += av[kk] * w[kk][0].y;
                    acc[i][2] += av[kk] * w[kk][0].z;
                    acc[i][3] += av[kk] * w[kk][0].w;
                    acc[i][4] += av[kk] * w[kk][1].x;
                    acc[i][5] += av[kk] * w[kk][1].y;
                    acc[i][6] += av[kk] * w[kk][1].z;
                    acc[i][7] += av[kk] * w[kk][1].w;
                }
            }
        }
    }
#pragma unroll
    for (int i = 0; i < 8; i++) {
        int r = r0 + r8 + i;
        if (r < n) {
            ushort4 o0, o1;
            o0.x = f2bf(acc[i][0]); o0.y = f2bf(acc[i][1]);
            o0.z = f2bf(acc[i][2]); o0.w = f2bf(acc[i][3]);
            o1.x = f2bf(acc[i][4]); o1.y = f2bf(acc[i][5]);
            o1.z = f2bf(acc[i][6]); o1.w = f2bf(acc[i][7]);
            *(ushort4*)&C[(size_t)r * 128 + c8] = o0;
            *(ushort4*)&C[(size_t)r * 128 + c8 + 4] = o1;
        }
    }
}

// --- pull aggregation, dim=128, bf16 H, f32 accumulate --------------------
__global__ __launch_bounds__(256) void k_agg128(const ushort_t* __restrict__ H,
                                                const int* __restrict__ rowptr,
                                                const int* __restrict__ csr_src,
                                                const float* __restrict__ dis,
                                                const float* __restrict__ bias,
                                                float* __restrict__ O, int n, int do_relu) {
    int wid = threadIdx.x >> 6;
    int lane = threadIdx.x & 63;
    int v = blockIdx.x * 4 + wid;
    if (v >= n) return;

    float dv = dis[v];
    float sw = dv * dv;
    uint_t h2 = ((const uint_t*)(H + (size_t)v * 128))[lane];
    float ax = bf_lo(h2) * sw, ay = bf_hi(h2) * sw;

    int e = rowptr[v], end = rowptr[v + 1];
    for (; e + 4 <= end; e += 4) {
        int s0 = csr_src[e], s1 = csr_src[e + 1], s2 = csr_src[e + 2], s3 = csr_src[e + 3];
        float w0 = dis[s0] * dv, w1 = dis[s1] * dv, w2 = dis[s2] * dv, w3 = dis[s3] * dv;
        uint_t a0 = ((const uint_t*)(H + (size_t)s0 * 128))[lane];
        uint_t a1 = ((const uint_t*)(H + (size_t)s1 * 128))[lane];
        uint_t a2 = ((const uint_t*)(H + (size_t)s2 * 128))[lane];
        uint_t a3 = ((const uint_t*)(H + (size_t)s3 * 128))[lane];
        ax += bf_lo(a0) * w0 + bf_lo(a1) * w1 + bf_lo(a2) * w2 + bf_lo(a3) * w3;
        ay += bf_hi(a0) * w0 + bf_hi(a1) * w1 + bf_hi(a2) * w2 + bf_hi(a3) * w3;
    }
    for (; e < end; e++) {
        int sI = csr_src[e];
        float w = dis[sI] * dv;
        uint_t a = ((const uint_t*)(H + (size_t)sI * 128))[lane];
        ax += bf_lo(a) * w;
        ay += bf_hi(a) * w;
    }

    float2 b2 = ((const float2*)bias)[lane];
    ax += b2.x;
    ay += b2.y;
    if (do_relu) {
        ax = fmaxf(ax, 0.f);
        ay = fmaxf(ay, 0.f);
    }
    ((float2*)(O + (size_t)v * 128))[lane] = make_float2(ax, ay);
}

// --- T[n x 2] = A[n x 128] @ W3[128 x 2] ----------------------------------
__global__ __launch_bounds__(256) void k_gemm_out(const float* __restrict__ A,
                                                  const float* __restrict__ W,
                                                  float* __restrict__ T, int n) {
    __shared__ float Wls[256];
    if (threadIdx.x < 256) Wls[threadIdx.x] = W[threadIdx.x];
    __syncthreads();
    int v = blockIdx.x * blockDim.x + threadIdx.x;
    if (v >= n) return;
    const float4* Av = (const float4*)(A + (size_t)v * 128);
    float acc0 = 0.f, acc1 = 0.f;
#pragma unroll
    for (int i = 0; i < 32; i++) {
        float4 a = Av[i];
        int k = i * 4;
        acc0 += a.x * Wls[(k + 0) * 2] + a.y * Wls[(k + 1) * 2] +
                a.z * Wls[(k + 2) * 2] + a.w * Wls[(k + 3) * 2];
        acc1 += a.x * Wls[(k + 0) * 2 + 1] + a.y * Wls[(k + 1) * 2 + 1] +
                a.z * Wls[(k + 2) * 2 + 1] + a.w * Wls[(k + 3) * 2 + 1];
    }
    ((float2*)T)[v] = make_float2(acc0, acc1);
}

// --- final aggregation, dim=2, writes d_out -------------------------------
__global__ __launch_bounds__(256) void k_agg2(const float* __restrict__ T,
                                              const int* __restrict__ rowptr,
                                              const int* __restrict__ csr_src,
                                              const float* __restrict__ dis,
                                              const float* __restrict__ b3,
                                              float* __restrict__ out, int n) {
    int v = blockIdx.x * blockDim.x + threadIdx.x;
    if (v >= n) return;
    float dv = dis[v];
    float sw = dv * dv;
    float2 tv = ((const float2*)T)[v];
    float a0 = tv.x * sw, a1 = tv.y * sw;
    int end = rowptr[v + 1];
    for (int e = rowptr[v]; e < end; e++) {
        int s = csr_src[e];
        float w = dis[s] * dv;
        float2 hs = ((const float2*)T)[s];
        a0 += hs.x * w;
        a1 += hs.y * w;
    }
    ((float2*)out)[v] = make_float2(a0 + b3[0], a1 + b3[1]);
}

extern "C" void kernel_launch(void* const* d_in, const int* in_sizes, int n_in,
                              void* d_out, int out_size, void* d_ws, size_t ws_size,
                              hipStream_t stream) {
    const float* x  = (const float*)d_in[0];
    const int* edge = (const int*)d_in[1];
    const float* W1 = (const float*)d_in[2];
    const float* b1 = (const float*)d_in[3];
    const float* W2 = (const float*)d_in[4];
    const float* b2 = (const float*)d_in[5];
    const float* W3 = (const float*)d_in[6];
    const float* b3 = (const float*)d_in[7];

    const int n = in_sizes[0] / 128;   // 50000
    const int E = in_sizes[1] / 2;     // 800000
    const int NB = (n + 255) >> 8;     // 196 buckets
    const int* src = edge;
    const int* dst = edge + E;

    // Workspace carve (aligned 256B). ~45.6 MB total.
    char* p = (char*)d_ws;
    auto alloc = [&](size_t bytes) -> void* {
        void* r = (void*)p;
        p += ((bytes + 255) / 256) * 256;
        return r;
    };
    int*      rowptr   = (int*)alloc((size_t)(n + 1) * 4);
    float*    dis      = (float*)alloc((size_t)n * 4);
    int*      cntmat   = (int*)alloc((size_t)NBLK * NB * 4);
    int*      bktbase  = (int*)alloc((size_t)(NB + 1) * 4);
    uint_t*   bucketed = (uint_t*)alloc((size_t)E * 4);
    int*      csr_src  = (int*)alloc((size_t)E * 4);
    float*    t3       = (float*)alloc((size_t)n * 2 * 4);
    ushort_t* Hbf      = (ushort_t*)alloc((size_t)n * 128 * 2);
    float*    Af       = (float*)alloc((size_t)n * 128 * 4);
    (void)ws_size;

    const int nblk = (n + 255) / 256;

    // --- CSR build (4 kernels, no global atomics) ---
    k_bcount<<<NBLK, 256, 0, stream>>>(dst, E, cntmat, NB);
    k_bscan<<<1, 256, 0, stream>>>(cntmat, bktbase, rowptr, NB, n, E);
    k_bfill<<<NBLK, 256, 0, stream>>>(src, dst, E, cntmat, bktbase, bucketed, NB);
    k_csort<<<NB, 256, 0, stream>>>(bucketed, bktbase, rowptr, dis, csr_src, n);

    const int gblk = (n + 127) / 128;
    const int ablk = (n + 3) / 4;

    // --- Layer 1 ---
    k_gemm128<<<gblk, 256, 0, stream>>>(x, W1, Hbf, n);
    k_agg128<<<ablk, 256, 0, stream>>>(Hbf, rowptr, csr_src, dis, b1, Af, n, 1);
    // --- Layer 2 ---
    k_gemm128<<<gblk, 256, 0, stream>>>(Af, W2, Hbf, n);
    k_agg128<<<ablk, 256, 0, stream>>>(Hbf, rowptr, csr_src, dis, b2, Af, n, 1);
    // --- Layer 3 (transform first: aggregation is linear) ---
    k_gemm_out<<<nblk, 256, 0, stream>>>(Af, W3, t3, n);
    k_agg2<<<nblk, 256, 0, stream>>>(t3, rowptr, csr_src, dis, b3, (float*)d_out, n);
}

// Round 14
// 298.295 us; speedup vs baseline: 1.0975x; 1.0975x over previous
//
#include <hip/hip_runtime.h>

// ---------------------------------------------------------------------------
// StandardGCN: 3-layer GCN, N=50000 nodes, E=800000 edges, D=H=128, OUT=2.
//   CSR build via deterministic 2-level bucket sort (NO global atomics).
//   gemm128: f32 GEMM, 64-row tiles (round-10 geometry: c4=(t&31)*4 stride-16B
//     W reads = measured 0 bank conflicts), k-unrolled x4 with float4 A reads
//     (round-13's 8-wide col blocking caused 3.2M 4-way LDS conflicts; round-10
//     scalar A reads were LDS-issue-bound: this keeps the conflict-free W
//     pattern AND vector A loads -> VALU-bound).
//   agg128: pull aggregation over bf16 H (f32 accum). Layer 3 transforms
//   first (128->2) then aggregates.
// ---------------------------------------------------------------------------

typedef unsigned short ushort_t;
typedef unsigned int uint_t;

#define NBLK 128          // blocks for bcount/bfill
#define BCAP 6144         // per-bucket LDS capacity (mean 4096, +32 sigma)

static __device__ __forceinline__ ushort_t f2bf(float f) {
    uint_t u = __float_as_uint(f);
    u += 0x7FFFu + ((u >> 16) & 1u);   // round-to-nearest-even
    return (ushort_t)(u >> 16);
}
static __device__ __forceinline__ float bf_lo(uint_t u) {
    return __uint_as_float(u << 16);
}
static __device__ __forceinline__ float bf_hi(uint_t u) {
    return __uint_as_float(u & 0xFFFF0000u);
}

// --- pass 1: per-block bucket histogram (no global atomics) ---------------
__global__ __launch_bounds__(256) void k_bcount(const int* __restrict__ dst, int E,
                                                int* __restrict__ cntmat, int NB) {
    __shared__ int hist[256];
    int t = threadIdx.x;
    hist[t] = 0;
    __syncthreads();
    int chunk = (E + NBLK - 1) / NBLK;
    int e0 = blockIdx.x * chunk;
    int e1 = min(e0 + chunk, E);
    for (int e = e0 + t; e < e1; e += 256) {
        atomicAdd(&hist[dst[e] >> 8], 1);
    }
    __syncthreads();
    if (t < NB) cntmat[blockIdx.x * NB + t] = hist[t];
}

// --- pass 2: column scan of cntmat + bucket base scan ---------------------
__global__ __launch_bounds__(256) void k_bscan(int* __restrict__ cntmat,
                                               int* __restrict__ bktbase,
                                               int* __restrict__ rowptr,
                                               int NB, int n, int E) {
    __shared__ int s[256];
    int t = threadIdx.x;
    int acc = 0;
    if (t < NB) {
        for (int r = 0; r < NBLK; r++) {
            int idx = r * NB + t;
            int c = cntmat[idx];
            cntmat[idx] = acc;    // within-bucket cross-block exclusive offset
            acc += c;
        }
    }
    s[t] = acc;                   // column total (0 for t >= NB)
    __syncthreads();
    for (int off = 1; off < 256; off <<= 1) {
        int u = (t >= off) ? s[t - off] : 0;
        __syncthreads();
        s[t] += u;
        __syncthreads();
    }
    if (t <= NB) bktbase[t] = s[t] - ((t < NB) ? acc : 0);  // exclusive; [NB]=E
    if (t == 0) rowptr[n] = E;
}

// --- pass 3: binned scatter into bucketed[] (LDS claims, run-coalesced) ---
__global__ __launch_bounds__(256) void k_bfill(const int* __restrict__ src,
                                               const int* __restrict__ dst, int E,
                                               const int* __restrict__ cntmat,
                                               const int* __restrict__ bktbase,
                                               uint_t* __restrict__ bucketed, int NB) {
    __shared__ int runb[256];
    __shared__ int bb[257];
    __shared__ int cur[256];
    int t = threadIdx.x;
    if (t < NB) {
        runb[t] = cntmat[blockIdx.x * NB + t];
        cur[t] = 0;
    }
    if (t < NB + 1) bb[t] = bktbase[t];
    __syncthreads();
    int chunk = (E + NBLK - 1) / NBLK;
    int e0 = blockIdx.x * chunk;
    int e1 = min(e0 + chunk, E);
    for (int e = e0 + t; e < e1; e += 256) {
        int d = dst[e];
        int b = d >> 8;
        int slot = atomicAdd(&cur[b], 1);
        bucketed[bb[b] + runb[b] + slot] = ((uint_t)src[e] << 8) | (uint_t)(d & 255);
    }
}

// --- pass 4: per-bucket counting sort -> csr_src, rowptr, dis -------------
__global__ __launch_bounds__(256) void k_csort(const uint_t* __restrict__ bucketed,
                                               const int* __restrict__ bktbase,
                                               int* __restrict__ rowptr,
                                               float* __restrict__ dis,
                                               int* __restrict__ csr_src, int n) {
    __shared__ int ncnt[256];
    __shared__ int s[256];
    __shared__ int cur[256];
    __shared__ int sorted[BCAP];
    int t = threadIdx.x;
    int b = blockIdx.x;
    int base = bktbase[b];
    int cnt_b = bktbase[b + 1] - base;
    int d0 = b << 8;

    ncnt[t] = 0;
    __syncthreads();
    for (int i = t; i < cnt_b; i += 256) {
        atomicAdd(&ncnt[bucketed[base + i] & 255u], 1);
    }
    __syncthreads();
    int own = ncnt[t];
    s[t] = own;
    __syncthreads();
    for (int off = 1; off < 256; off <<= 1) {
        int u = (t >= off) ? s[t - off] : 0;
        __syncthreads();
        s[t] += u;
        __syncthreads();
    }
    int ex = s[t] - own;          // exclusive within-bucket offset
    cur[t] = ex;
    int d = d0 + t;
    if (d < n) {
        rowptr[d] = base + ex;
        dis[d] = rsqrtf((float)(own + 1));
    }
    __syncthreads();
    for (int i = t; i < cnt_b; i += 256) {
        uint_t ent = bucketed[base + i];
        int p = atomicAdd(&cur[ent & 255u], 1);
        if (p < BCAP) sorted[p] = (int)(ent >> 8);
    }
    __syncthreads();
    for (int i = t; i < cnt_b; i += 256) {
        csr_src[base + i] = sorted[i];
    }
}

// --- C[n x 128](bf16) = A[n x 128](f32) @ W[128 x 128](f32) ---------------
// 64 rows/block, 256 threads, 8 rows x 4 cols per thread (round-10 geometry),
// k-unrolled x4 with float4 A reads. LDS 48KB -> 3 blocks/CU.
__global__ __launch_bounds__(256) void k_gemm128(const float* __restrict__ A,
                                                 const float* __restrict__ W,
                                                 ushort_t* __restrict__ C, int n) {
    __shared__ float As[64 * 128];
    __shared__ float Wc[32 * 128];
    int t = threadIdx.x;
    int r0 = blockIdx.x * 64;

    // stage A rows r0..r0+63: 2048 float4, 8 per thread
    for (int i = t; i < 64 * 32; i += 256) {
        int gr = r0 + (i >> 5);
        float4 val = (gr < n) ? ((const float4*)A)[(size_t)gr * 32 + (i & 31)]
                              : make_float4(0.f, 0.f, 0.f, 0.f);
        ((float4*)As)[i] = val;
    }

    int c4 = (t & 31) * 4;       // 4 consecutive cols (stride-16B W reads: conflict-free)
    int r8 = (t >> 5) * 8;       // 8 consecutive rows (A reads broadcast per wave)
    float acc[8][4] = {};

    for (int kc = 0; kc < 4; kc++) {
        __syncthreads();
        // stage W rows kc*32..kc*32+31: 1024 float4, 4 per thread
        for (int i = t; i < 32 * 32; i += 256) {
            ((float4*)Wc)[i] = ((const float4*)W)[kc * 1024 + i];
        }
        __syncthreads();
#pragma unroll
        for (int k4 = 0; k4 < 32; k4 += 4) {
            float4 a[8];
#pragma unroll
            for (int i = 0; i < 8; i++) {
                a[i] = *(const float4*)&As[(r8 + i) * 128 + kc * 32 + k4];
            }
            float4 w[4];
#pragma unroll
            for (int kk = 0; kk < 4; kk++) {
                w[kk] = *(const float4*)&Wc[(k4 + kk) * 128 + c4];
            }
#pragma unroll
            for (int i = 0; i < 8; i++) {
                float av[4] = {a[i].x, a[i].y, a[i].z, a[i].w};
#pragma unroll
                for (int kk = 0; kk < 4; kk++) {
                    acc[i][0] += av[kk] * w[kk].x;
                    acc[i][1] += av[kk] * w[kk].y;
                    acc[i][2] += av[kk] * w[kk].z;
                    acc[i][3] += av[kk] * w[kk].w;
                }
            }
        }
    }
#pragma unroll
    for (int i = 0; i < 8; i++) {
        int r = r0 + r8 + i;
        if (r < n) {
            ushort4 o;
            o.x = f2bf(acc[i][0]);
            o.y = f2bf(acc[i][1]);
            o.z = f2bf(acc[i][2]);
            o.w = f2bf(acc[i][3]);
            *(ushort4*)&C[(size_t)r * 128 + c4] = o;
        }
    }
}

// --- pull aggregation, dim=128, bf16 H, f32 accumulate --------------------
__global__ __launch_bounds__(256) void k_agg128(const ushort_t* __restrict__ H,
                                                const int* __restrict__ rowptr,
                                                const int* __restrict__ csr_src,
                                                const float* __restrict__ dis,
                                                const float* __restrict__ bias,
                                                float* __restrict__ O, int n, int do_relu) {
    int wid = threadIdx.x >> 6;
    int lane = threadIdx.x & 63;
    int v = blockIdx.x * 4 + wid;
    if (v >= n) return;

    float dv = dis[v];
    float sw = dv * dv;
    uint_t h2 = ((const uint_t*)(H + (size_t)v * 128))[lane];
    float ax = bf_lo(h2) * sw, ay = bf_hi(h2) * sw;

    int e = rowptr[v], end = rowptr[v + 1];
    for (; e + 4 <= end; e += 4) {
        int s0 = csr_src[e], s1 = csr_src[e + 1], s2 = csr_src[e + 2], s3 = csr_src[e + 3];
        float w0 = dis[s0] * dv, w1 = dis[s1] * dv, w2 = dis[s2] * dv, w3 = dis[s3] * dv;
        uint_t a0 = ((const uint_t*)(H + (size_t)s0 * 128))[lane];
        uint_t a1 = ((const uint_t*)(H + (size_t)s1 * 128))[lane];
        uint_t a2 = ((const uint_t*)(H + (size_t)s2 * 128))[lane];
        uint_t a3 = ((const uint_t*)(H + (size_t)s3 * 128))[lane];
        ax += bf_lo(a0) * w0 + bf_lo(a1) * w1 + bf_lo(a2) * w2 + bf_lo(a3) * w3;
        ay += bf_hi(a0) * w0 + bf_hi(a1) * w1 + bf_hi(a2) * w2 + bf_hi(a3) * w3;
    }
    for (; e < end; e++) {
        int sI = csr_src[e];
        float w = dis[sI] * dv;
        uint_t a = ((const uint_t*)(H + (size_t)sI * 128))[lane];
        ax += bf_lo(a) * w;
        ay += bf_hi(a) * w;
    }

    float2 b2 = ((const float2*)bias)[lane];
    ax += b2.x;
    ay += b2.y;
    if (do_relu) {
        ax = fmaxf(ax, 0.f);
        ay = fmaxf(ay, 0.f);
    }
    ((float2*)(O + (size_t)v * 128))[lane] = make_float2(ax, ay);
}

// --- T[n x 2] = A[n x 128] @ W3[128 x 2] ----------------------------------
__global__ __launch_bounds__(256) void k_gemm_out(const float* __restrict__ A,
                                                  const float* __restrict__ W,
                                                  float* __restrict__ T, int n) {
    __shared__ float Wls[256];
    if (threadIdx.x < 256) Wls[threadIdx.x] = W[threadIdx.x];
    __syncthreads();
    int v = blockIdx.x * blockDim.x + threadIdx.x;
    if (v >= n) return;
    const float4* Av = (const float4*)(A + (size_t)v * 128);
    float acc0 = 0.f, acc1 = 0.f;
#pragma unroll
    for (int i = 0; i < 32; i++) {
        float4 a = Av[i];
        int k = i * 4;
        acc0 += a.x * Wls[(k + 0) * 2] + a.y * Wls[(k + 1) * 2] +
                a.z * Wls[(k + 2) * 2] + a.w * Wls[(k + 3) * 2];
        acc1 += a.x * Wls[(k + 0) * 2 + 1] + a.y * Wls[(k + 1) * 2 + 1] +
                a.z * Wls[(k + 2) * 2 + 1] + a.w * Wls[(k + 3) * 2 + 1];
    }
    ((float2*)T)[v] = make_float2(acc0, acc1);
}

// --- final aggregation, dim=2, writes d_out -------------------------------
__global__ __launch_bounds__(256) void k_agg2(const float* __restrict__ T,
                                              const int* __restrict__ rowptr,
                                              const int* __restrict__ csr_src,
                                              const float* __restrict__ dis,
                                              const float* __restrict__ b3,
                                              float* __restrict__ out, int n) {
    int v = blockIdx.x * blockDim.x + threadIdx.x;
    if (v >= n) return;
    float dv = dis[v];
    float sw = dv * dv;
    float2 tv = ((const float2*)T)[v];
    float a0 = tv.x * sw, a1 = tv.y * sw;
    int end = rowptr[v + 1];
    for (int e = rowptr[v]; e < end; e++) {
        int s = csr_src[e];
        float w = dis[s] * dv;
        float2 hs = ((const float2*)T)[s];
        a0 += hs.x * w;
        a1 += hs.y * w;
    }
    ((float2*)out)[v] = make_float2(a0 + b3[0], a1 + b3[1]);
}

extern "C" void kernel_launch(void* const* d_in, const int* in_sizes, int n_in,
                              void* d_out, int out_size, void* d_ws, size_t ws_size,
                              hipStream_t stream) {
    const float* x  = (const float*)d_in[0];
    const int* edge = (const int*)d_in[1];
    const float* W1 = (const float*)d_in[2];
    const float* b1 = (const float*)d_in[3];
    const float* W2 = (const float*)d_in[4];
    const float* b2 = (const float*)d_in[5];
    const float* W3 = (const float*)d_in[6];
    const float* b3 = (const float*)d_in[7];

    const int n = in_sizes[0] / 128;   // 50000
    const int E = in_sizes[1] / 2;     // 800000
    const int NB = (n + 255) >> 8;     // 196 buckets
    const int* src = edge;
    const int* dst = edge + E;

    // Workspace carve (aligned 256B). ~45.6 MB total.
    char* p = (char*)d_ws;
    auto alloc = [&](size_t bytes) -> void* {
        void* r = (void*)p;
        p += ((bytes + 255) / 256) * 256;
        return r;
    };
    int*      rowptr   = (int*)alloc((size_t)(n + 1) * 4);
    float*    dis      = (float*)alloc((size_t)n * 4);
    int*      cntmat   = (int*)alloc((size_t)NBLK * NB * 4);
    int*      bktbase  = (int*)alloc((size_t)(NB + 1) * 4);
    uint_t*   bucketed = (uint_t*)alloc((size_t)E * 4);
    int*      csr_src  = (int*)alloc((size_t)E * 4);
    float*    t3       = (float*)alloc((size_t)n * 2 * 4);
    ushort_t* Hbf      = (ushort_t*)alloc((size_t)n * 128 * 2);
    float*    Af       = (float*)alloc((size_t)n * 128 * 4);
    (void)ws_size;

    const int nblk = (n + 255) / 256;

    // --- CSR build (4 kernels, no global atomics) ---
    k_bcount<<<NBLK, 256, 0, stream>>>(dst, E, cntmat, NB);
    k_bscan<<<1, 256, 0, stream>>>(cntmat, bktbase, rowptr, NB, n, E);
    k_bfill<<<NBLK, 256, 0, stream>>>(src, dst, E, cntmat, bktbase, bucketed, NB);
    k_csort<<<NB, 256, 0, stream>>>(bucketed, bktbase, rowptr, dis, csr_src, n);

    const int gblk = (n + 63) / 64;
    const int ablk = (n + 3) / 4;

    // --- Layer 1 ---
    k_gemm128<<<gblk, 256, 0, stream>>>(x, W1, Hbf, n);
    k_agg128<<<ablk, 256, 0, stream>>>(Hbf, rowptr, csr_src, dis, b1, Af, n, 1);
    // --- Layer 2 ---
    k_gemm128<<<gblk, 256, 0, stream>>>(Af, W2, Hbf, n);
    k_agg128<<<ablk, 256, 0, stream>>>(Hbf, rowptr, csr_src, dis, b2, Af, n, 1);
    // --- Layer 3 (transform first: aggregation is linear) ---
    k_gemm_out<<<nblk, 256, 0, stream>>>(Af, W3, t3, n);
    k_agg2<<<nblk, 256, 0, stream>>>(t3, rowptr, csr_src, dis, b3, (float*)d_out, n);
}